// Round 11
// baseline (587.424 us; speedup 1.0000x reference)
//
#include <hip/hip_runtime.h>

// ---------------------------------------------------------------------------
// PointTransformerBlock, MI355X.  R11 = best-of-measured composition:
//  - k_edge: R8 body EXACTLY (measured 249us / VGPR 68 / occ 33%): single
//    64-edge tile per block, in-kernel transposed weight staging as latency
//    filler, pre-barrier q/k gathers, v prefetch, wave-private LDS rows (no
//    tail barrier), segmented per-dst-run atomics.  R9/R10's cross-tile
//    register pipelines REJECTED: prefetch state drops 3->2 blocks/CU
//    (VGPR 100-108, occ 22%) and lost TLP beats gained ILP (263/306us).
//  - Tail: R10 launcher (hist fused into k_prep, scan1 into k_node, scan2
//    into scan3, zeroing into scatter) -- measured ~278us.
//  MFMA layouts (HW-verified, guide §3): A[m=lane&15][k=quad*8+j],
//  B[k=quad*8+j][n=lane&15], C/D col=lane&15 row=quad*4+reg.
// ---------------------------------------------------------------------------

typedef __bf16 bf16x8 __attribute__((ext_vector_type(8)));
typedef float f32x4 __attribute__((ext_vector_type(4)));

__device__ inline unsigned short f2bf(float f) {
  return __builtin_bit_cast(unsigned short, (__bf16)f);   // v_cvt (RNE)
}
__device__ inline float bf2f(unsigned short s) {
  return __uint_as_float(((unsigned int)s) << 16);
}
__device__ inline bf16x8 ld_bf8(const unsigned short* p) {
  union { uint4 i; bf16x8 v; } u;
  u.i = *(const uint4*)p;
  return u.v;
}

// --------------------- prep kernel with fused histogram --------------------

__global__ __launch_bounds__(256) void k_prep_hist(
    const float* __restrict__ W_in, const float* __restrict__ W_dst,
    const float* __restrict__ W_src, const float* __restrict__ W_lin,
    const float* __restrict__ pn_W2, const float* __restrict__ an_W1,
    const float* __restrict__ an_W2, const float* __restrict__ W_out,
    unsigned short* __restrict__ wt,
    const int* __restrict__ dst, int* __restrict__ hist, int E) {
  int t = threadIdx.x;
  if (blockIdx.x >= 8) {
    int e = (blockIdx.x - 8) * 256 + t;
    if (e < E) atomicAdd(&hist[dst[e]], 1);
    return;
  }
  const float* Ws[8] = {W_in, W_dst, W_src, W_lin, pn_W2, an_W1, an_W2, W_out};
  const float* W = Ws[blockIdx.x];
  unsigned short* o = wt + (size_t)blockIdx.x * 4608;
#pragma unroll
  for (int i = 0; i < 16; ++i) {
    int e = i * 256 + t;           // e = k*64 + n  (coalesced read)
    int k = e >> 6, n = e & 63;
    o[n * 72 + k] = f2bf(W[e]);
  }
}

// ------------------------------ sort kernels -------------------------------

// scan3 with inline block-offset: reduce bsum[0..blockIdx) in-block.
// Requires gridDim <= 256 (N <= 262144).
__global__ __launch_bounds__(256) void k_scan3(
    const int* __restrict__ incl, const int* __restrict__ hist,
    const int* __restrict__ bsum, int* __restrict__ cursor, int N) {
  __shared__ int red[256];
  int t = threadIdx.x;
  red[t] = (t < (int)blockIdx.x) ? bsum[t] : 0;
  __syncthreads();
#pragma unroll
  for (int off = 128; off; off >>= 1) {
    if (t < off) red[t] += red[t + off];
    __syncthreads();
  }
  int bo = red[0];
  int base = blockIdx.x * 1024 + t * 4;
#pragma unroll
  for (int i = 0; i < 4; ++i) {
    int id = base + i;
    if (id < N) cursor[id] = bo + incl[id] - hist[id];
  }
}

// scatter with fused sg/accg zeroing (sibling blocks).
__global__ void k_scatter_zero(const int* __restrict__ src,
                               const int* __restrict__ dst,
                               int* __restrict__ cursor,
                               int2* __restrict__ spair, int E,
                               float4* __restrict__ zbase, int zcount,
                               int scatterBlocks) {
  int t = threadIdx.x;
  if ((int)blockIdx.x >= scatterBlocks) {
    int i = ((int)blockIdx.x - scatterBlocks) * 256 + t;
    if (i < zcount) zbase[i] = make_float4(0.f, 0.f, 0.f, 0.f);
    return;
  }
  int e = blockIdx.x * 256 + t;
  if (e < E) {
    int s = src[e], d = dst[e];
    int p = atomicAdd(&cursor[d], 1);
    spair[p] = make_int2(s, d);
  }
}

// ---------------- node kernel (MFMA) with fused scan1 ----------------------

__global__ __launch_bounds__(256) void k_node(
    const float* __restrict__ x, const unsigned short* __restrict__ wt,
    const float* __restrict__ b_in, const float* __restrict__ ln_g,
    const float* __restrict__ ln_b,
    float* __restrict__ qg, float* __restrict__ kg, float* __restrict__ vg,
    int N, const int* __restrict__ hist, int* __restrict__ incl,
    int* __restrict__ bsum, int nodeBlocks) {
  int t = threadIdx.x;

  // ---- fused scan1 blocks ----
  if ((int)blockIdx.x >= nodeBlocks) {
    __shared__ int sd[256];
    int bid = blockIdx.x - nodeBlocks;
    int base = bid * 1024 + t * 4;
    int v[4]; int ts = 0;
#pragma unroll
    for (int i = 0; i < 4; ++i) {
      int idx = base + i;
      v[i] = (idx < N) ? hist[idx] : 0;
      ts += v[i];
    }
    sd[t] = ts;
    __syncthreads();
    for (int off = 1; off < 256; off <<= 1) {
      int xv = (t >= off) ? sd[t - off] : 0;
      __syncthreads();
      sd[t] += xv;
      __syncthreads();
    }
    int run = sd[t] - ts;
#pragma unroll
    for (int i = 0; i < 4; ++i) {
      run += v[i];
      int idx = base + i;
      if (idx < N) incl[idx] = run;
    }
    if (t == 255) bsum[bid] = sd[255];
    return;
  }

  __shared__ __align__(16) unsigned short WALL[4 * 64 * 72];
  __shared__ __align__(16) unsigned short HT[64 * 72];
  __shared__ float LNG[64], LNB[64], BIN[64];

  int lane = t & 63, wv = t >> 6;
  int nl = lane & 15, q = lane >> 4;
  int w16 = wv * 16;
  int n0g = blockIdx.x * 64;

  {
    const uint4* s4 = (const uint4*)wt;
    uint4* d4 = (uint4*)WALL;
#pragma unroll
    for (int i = 0; i < 9; ++i) d4[i * 256 + t] = s4[i * 256 + t];
  }
  if (t < 64) { LNG[t] = ln_g[t]; LNB[t] = ln_b[t]; BIN[t] = b_in[t]; }

  int row = n0g + w16 + nl;
  bf16x8 a[2];
#pragma unroll
  for (int s = 0; s < 2; ++s) {
    union { unsigned short u[8]; bf16x8 v; } fa;
    if (row < N) {
      int kb = s * 32 + q * 8;
      float4 xa = *(const float4*)(x + (size_t)row * 64 + kb);
      float4 xb = *(const float4*)(x + (size_t)row * 64 + kb + 4);
      fa.u[0] = f2bf(xa.x); fa.u[1] = f2bf(xa.y);
      fa.u[2] = f2bf(xa.z); fa.u[3] = f2bf(xa.w);
      fa.u[4] = f2bf(xb.x); fa.u[5] = f2bf(xb.y);
      fa.u[6] = f2bf(xb.z); fa.u[7] = f2bf(xb.w);
    } else {
#pragma unroll
      for (int j = 0; j < 8; ++j) fa.u[j] = 0;
    }
    a[s] = fa.v;
  }
  __syncthreads();

  f32x4 h[4];
#pragma unroll
  for (int n0 = 0; n0 < 4; ++n0) {
    f32x4 acc = {0.f, 0.f, 0.f, 0.f};
    acc = __builtin_amdgcn_mfma_f32_16x16x32_bf16(
        a[0], ld_bf8(&WALL[(n0 * 16 + nl) * 72 + q * 8]), acc, 0, 0, 0);
    acc = __builtin_amdgcn_mfma_f32_16x16x32_bf16(
        a[1], ld_bf8(&WALL[(n0 * 16 + nl) * 72 + 32 + q * 8]), acc, 0, 0, 0);
    float bias = BIN[n0 * 16 + nl];
#pragma unroll
    for (int r = 0; r < 4; ++r) acc[r] = fmaxf(acc[r] + bias, 0.f);
    h[n0] = acc;
  }

#pragma unroll
  for (int r = 0; r < 4; ++r) {
    float sv = 0.f, sq = 0.f;
#pragma unroll
    for (int n0 = 0; n0 < 4; ++n0) {
      float v = h[n0][r];
      sv += v; sq += v * v;
    }
    sv += __shfl_xor(sv, 1); sq += __shfl_xor(sq, 1);
    sv += __shfl_xor(sv, 2); sq += __shfl_xor(sq, 2);
    sv += __shfl_xor(sv, 4); sq += __shfl_xor(sq, 4);
    sv += __shfl_xor(sv, 8); sq += __shfl_xor(sq, 8);
    float mu = sv * (1.f / 64.f);
    float var = sq * (1.f / 64.f) - mu * mu;
    float rs = rsqrtf(var + 1e-5f);
    int crow = w16 + q * 4 + r;
#pragma unroll
    for (int n0 = 0; n0 < 4; ++n0) {
      int col = n0 * 16 + nl;
      float hv = (h[n0][r] - mu) * rs * LNG[col] + LNB[col];
      HT[crow * 72 + col] = f2bf(hv);
    }
  }

  a[0] = ld_bf8(&HT[(w16 + nl) * 72 + q * 8]);
  a[1] = ld_bf8(&HT[(w16 + nl) * 72 + 32 + q * 8]);

  float* Og[3] = {qg, kg, vg};
#pragma unroll
  for (int m = 0; m < 3; ++m) {
    const unsigned short* Wm = WALL + (m + 1) * 4608;
#pragma unroll
    for (int n0 = 0; n0 < 4; ++n0) {
      f32x4 acc = {0.f, 0.f, 0.f, 0.f};
      acc = __builtin_amdgcn_mfma_f32_16x16x32_bf16(
          a[0], ld_bf8(&Wm[(n0 * 16 + nl) * 72 + q * 8]), acc, 0, 0, 0);
      acc = __builtin_amdgcn_mfma_f32_16x16x32_bf16(
          a[1], ld_bf8(&Wm[(n0 * 16 + nl) * 72 + 32 + q * 8]), acc, 0, 0, 0);
      int col = n0 * 16 + nl;
#pragma unroll
      for (int r = 0; r < 4; ++r) {
        int grow = n0g + w16 + q * 4 + r;
        if (grow < N) Og[m][(size_t)grow * 64 + col] = acc[r];
      }
    }
  }
}

// ------------------- edge kernel (MFMA, R8 body exactly) -------------------

__global__ __launch_bounds__(256) void k_edge(
    const int2* __restrict__ spair, const float* __restrict__ pos,
    const float* __restrict__ qg, const float* __restrict__ kg,
    const float* __restrict__ vg,
    const float* __restrict__ pn_W1, const float* __restrict__ pn_b1,
    const float* __restrict__ pn_W2, const float* __restrict__ pn_b2,
    const float* __restrict__ an_W1, const float* __restrict__ an_b1,
    const float* __restrict__ an_W2, const float* __restrict__ an_b2,
    float* __restrict__ sg, float* __restrict__ accg, int E) {
  __shared__ __align__(16) unsigned short WPN2[64 * 72];
  __shared__ __align__(16) unsigned short WAN1[64 * 72];
  __shared__ __align__(16) unsigned short WAN2[64 * 72];
  __shared__ __align__(16) unsigned short SD[64 * 72];   // delta (bf16)
  __shared__ __align__(16) unsigned short SB[64 * 72];   // a1, then ex (bf16)
  __shared__ float PD[64 * 4];
  __shared__ float W1[3 * 64];
  __shared__ float B1[64], B2[64], AB1[64], AB2[64];
  __shared__ int Ss[64], Sd[64];

  int t = threadIdx.x;
  int lane = t & 63, wv = t >> 6;
  int nl = lane & 15, q = lane >> 4;
  int w16 = wv * 16;
  long e0 = (long)blockIdx.x * 64;

  // ---- per-lane early gather: my A-frag row's q/k rows (pre-barrier) ----
  long er = e0 + w16 + nl;
  int2 my = (er < E) ? spair[er] : make_int2(0, 0);
  const float* qr = qg + (size_t)my.y * 64;
  const float* kr = kg + (size_t)my.x * 64;
  float4 qf[2][2], kf[2][2];
#pragma unroll
  for (int s = 0; s < 2; ++s) {
    int kb = s * 32 + q * 8;
    qf[s][0] = *(const float4*)(qr + kb);
    qf[s][1] = *(const float4*)(qr + kb + 4);
    kf[s][0] = *(const float4*)(kr + kb);
    kf[s][1] = *(const float4*)(kr + kb + 4);
  }

  // ---- stage weights bf16 [n][k] stride 72 (VALU filler over gather lat) --
  {
    int n = t & 63, k0 = (t >> 6) * 16;
#pragma unroll
    for (int i = 0; i < 16; ++i) {
      int k = k0 + i;
      WPN2[n * 72 + k] = f2bf(pn_W2[k * 64 + n]);
      WAN1[n * 72 + k] = f2bf(an_W1[k * 64 + n]);
      WAN2[n * 72 + k] = f2bf(an_W2[k * 64 + n]);
    }
  }
  if (t < 192) W1[t] = pn_W1[t];
  if (t < 64) {
    B1[t] = pn_b1[t];  B2[t] = pn_b2[t];
    AB1[t] = an_b1[t]; AB2[t] = an_b2[t];
    long e = e0 + t;
    int2 sd2 = (e < E) ? spair[e] : make_int2(0, 0);
    Ss[t] = sd2.x; Sd[t] = sd2.y;
    PD[t * 4 + 0] = pos[sd2.y * 3 + 0] - pos[sd2.x * 3 + 0];
    PD[t * 4 + 1] = pos[sd2.y * 3 + 1] - pos[sd2.x * 3 + 1];
    PD[t * 4 + 2] = pos[sd2.y * 3 + 2] - pos[sd2.x * 3 + 2];
  }
  __syncthreads();

  // ---- v prefetch for the reduction (rows wave-private: qq == wv) ----
  float vpre[16];
  {
    int c = t & 63, qq = t >> 6;
#pragma unroll
    for (int i = 0; i < 16; ++i)
      vpre[i] = vg[(size_t)Ss[qq * 16 + i] * 64 + c];
  }

  bf16x8 a[2];

  // ---- pos-MLP layer1 (K=3) straight into A-frag registers ----
  {
    int row = w16 + nl;
    float p0 = PD[row * 4 + 0], p1 = PD[row * 4 + 1], p2 = PD[row * 4 + 2];
#pragma unroll
    for (int s = 0; s < 2; ++s) {
      union { unsigned short u[8]; bf16x8 v; } fa;
      int kb = s * 32 + q * 8;
#pragma unroll
      for (int j = 0; j < 8; ++j) {
        int c = kb + j;
        float val = fmaf(p0, W1[c],
                    fmaf(p1, W1[64 + c],
                    fmaf(p2, W1[128 + c], B1[c])));
        fa.u[j] = f2bf(fmaxf(val, 0.f));
      }
      a[s] = fa.v;
    }
  }

  // ---- GEMM1: delta = relu(A1 @ pn_W2 + b2) -> SD (bf16) ----
#pragma unroll
  for (int n0 = 0; n0 < 4; ++n0) {
    f32x4 acc = {0.f, 0.f, 0.f, 0.f};
    acc = __builtin_amdgcn_mfma_f32_16x16x32_bf16(
        a[0], ld_bf8(&WPN2[(n0 * 16 + nl) * 72 + q * 8]), acc, 0, 0, 0);
    acc = __builtin_amdgcn_mfma_f32_16x16x32_bf16(
        a[1], ld_bf8(&WPN2[(n0 * 16 + nl) * 72 + 32 + q * 8]), acc, 0, 0, 0);
    int col = n0 * 16 + nl;
    float bias = B2[col];
#pragma unroll
    for (int r = 0; r < 4; ++r) {
      int row = w16 + q * 4 + r;
      SD[row * 72 + col] = f2bf(fmaxf(acc[r] + bias, 0.f));
    }
  }

  // ---- build ai = q[dst]-k[src]+delta in A-frag layout ----
  {
    int row = w16 + nl;
#pragma unroll
    for (int s = 0; s < 2; ++s) {
      int kb = s * 32 + q * 8;
      bf16x8 d8 = ld_bf8(&SD[row * 72 + kb]);
      union { unsigned short u[8]; bf16x8 v; } fa;
      fa.u[0] = f2bf(qf[s][0].x - kf[s][0].x + (float)d8[0]);
      fa.u[1] = f2bf(qf[s][0].y - kf[s][0].y + (float)d8[1]);
      fa.u[2] = f2bf(qf[s][0].z - kf[s][0].z + (float)d8[2]);
      fa.u[3] = f2bf(qf[s][0].w - kf[s][0].w + (float)d8[3]);
      fa.u[4] = f2bf(qf[s][1].x - kf[s][1].x + (float)d8[4]);
      fa.u[5] = f2bf(qf[s][1].y - kf[s][1].y + (float)d8[5]);
      fa.u[6] = f2bf(qf[s][1].z - kf[s][1].z + (float)d8[6]);
      fa.u[7] = f2bf(qf[s][1].w - kf[s][1].w + (float)d8[7]);
      a[s] = fa.v;
    }
  }

  // ---- GEMM2: a1 = relu(ai @ an_W1 + an_b1) -> SB (bf16) ----
#pragma unroll
  for (int n0 = 0; n0 < 4; ++n0) {
    f32x4 acc = {0.f, 0.f, 0.f, 0.f};
    acc = __builtin_amdgcn_mfma_f32_16x16x32_bf16(
        a[0], ld_bf8(&WAN1[(n0 * 16 + nl) * 72 + q * 8]), acc, 0, 0, 0);
    acc = __builtin_amdgcn_mfma_f32_16x16x32_bf16(
        a[1], ld_bf8(&WAN1[(n0 * 16 + nl) * 72 + 32 + q * 8]), acc, 0, 0, 0);
    int col = n0 * 16 + nl;
    float bias = AB1[col];
#pragma unroll
    for (int r = 0; r < 4; ++r) {
      int row = w16 + q * 4 + r;
      SB[row * 72 + col] = f2bf(fmaxf(acc[r] + bias, 0.f));
    }
  }

  // ---- GEMM3: alpha = relu(a1 @ an_W2 + an_b2); ex = exp(alpha) -> SB ----
  // (wave-private SB rows; DS ops in-order per wave, no barrier needed)
  a[0] = ld_bf8(&SB[(w16 + nl) * 72 + q * 8]);
  a[1] = ld_bf8(&SB[(w16 + nl) * 72 + 32 + q * 8]);
#pragma unroll
  for (int n0 = 0; n0 < 4; ++n0) {
    f32x4 acc = {0.f, 0.f, 0.f, 0.f};
    acc = __builtin_amdgcn_mfma_f32_16x16x32_bf16(
        a[0], ld_bf8(&WAN2[(n0 * 16 + nl) * 72 + q * 8]), acc, 0, 0, 0);
    acc = __builtin_amdgcn_mfma_f32_16x16x32_bf16(
        a[1], ld_bf8(&WAN2[(n0 * 16 + nl) * 72 + 32 + q * 8]), acc, 0, 0, 0);
    int col = n0 * 16 + nl;
    float bias = AB2[col];
#pragma unroll
    for (int r = 0; r < 4; ++r) {
      int row = w16 + q * 4 + r;
      long e = e0 + row;
      float al = fmaxf(acc[r] + bias, 0.f);
      float ex = (e < E) ? __expf(al) : 0.f;
      SB[row * 72 + col] = f2bf(ex);
    }
  }

  // ---- segmented per-dst-run reduction (rows wave-private: no barrier) ----
  {
    int c = t & 63, qq = t >> 6;
    int r0 = qq * 16;
    int cur = Sd[r0];
    float ssum = 0.f, asum = 0.f;
#pragma unroll
    for (int r = r0; r < r0 + 16; ++r) {
      int d = Sd[r];
      if (d != cur) {
        if (ssum != 0.f) {
          atomicAdd(&sg[(size_t)cur * 64 + c], ssum);
          atomicAdd(&accg[(size_t)cur * 64 + c], asum);
        }
        cur = d; ssum = 0.f; asum = 0.f;
      }
      float ex = bf2f(SB[r * 72 + c]);
      float pay = vpre[r - r0] + bf2f(SD[r * 72 + c]);
      ssum += ex;
      asum = fmaf(ex, pay, asum);
    }
    if (ssum != 0.f) {
      atomicAdd(&sg[(size_t)cur * 64 + c], ssum);
      atomicAdd(&accg[(size_t)cur * 64 + c], asum);
    }
  }
}

// ------------------------- out kernel (MFMA) -------------------------------

__global__ __launch_bounds__(256) void k_out(const float* __restrict__ accg,
                                             const float* __restrict__ sg,
                                             const unsigned short* __restrict__ wt,
                                             const float* __restrict__ b,
                                             float* __restrict__ out, int N) {
  __shared__ __align__(16) unsigned short WO[64 * 72];
  __shared__ float BO[64];
  int t = threadIdx.x;
  int lane = t & 63, wv = t >> 6;
  int nl = lane & 15, q = lane >> 4;
  int w16 = wv * 16;
  int n0g = blockIdx.x * 64;

  {
    const uint4* s4 = (const uint4*)(wt + 7 * 4608);  // matrix 7 = W_out
    uint4* d4 = (uint4*)WO;
#pragma unroll
    for (int i = 0; i < 3; ++i) {
      int idx = i * 256 + t;
      if (idx < 576) d4[idx] = s4[idx];
    }
  }
  if (t < 64) BO[t] = b[t];

  int row = n0g + w16 + nl;
  bf16x8 a[2];
#pragma unroll
  for (int s = 0; s < 2; ++s) {
    union { unsigned short u[8]; bf16x8 v; } fa;
    if (row < N) {
      int kb = s * 32 + q * 8;
      float4 na = *(const float4*)(accg + (size_t)row * 64 + kb);
      float4 nb = *(const float4*)(accg + (size_t)row * 64 + kb + 4);
      float4 da = *(const float4*)(sg + (size_t)row * 64 + kb);
      float4 db = *(const float4*)(sg + (size_t)row * 64 + kb + 4);
      fa.u[0] = f2bf(na.x / (da.x + 1e-16f));
      fa.u[1] = f2bf(na.y / (da.y + 1e-16f));
      fa.u[2] = f2bf(na.z / (da.z + 1e-16f));
      fa.u[3] = f2bf(na.w / (da.w + 1e-16f));
      fa.u[4] = f2bf(nb.x / (db.x + 1e-16f));
      fa.u[5] = f2bf(nb.y / (db.y + 1e-16f));
      fa.u[6] = f2bf(nb.z / (db.z + 1e-16f));
      fa.u[7] = f2bf(nb.w / (db.w + 1e-16f));
    } else {
#pragma unroll
      for (int j = 0; j < 8; ++j) fa.u[j] = 0;
    }
    a[s] = fa.v;
  }
  __syncthreads();

#pragma unroll
  for (int n0 = 0; n0 < 4; ++n0) {
    f32x4 acc = {0.f, 0.f, 0.f, 0.f};
    acc = __builtin_amdgcn_mfma_f32_16x16x32_bf16(
        a[0], ld_bf8(&WO[(n0 * 16 + nl) * 72 + q * 8]), acc, 0, 0, 0);
    acc = __builtin_amdgcn_mfma_f32_16x16x32_bf16(
        a[1], ld_bf8(&WO[(n0 * 16 + nl) * 72 + 32 + q * 8]), acc, 0, 0, 0);
    int col = n0 * 16 + nl;
    float bias = BO[col];
#pragma unroll
    for (int r = 0; r < 4; ++r) {
      int grow = n0g + w16 + q * 4 + r;
      if (grow < N) out[(size_t)grow * 64 + col] = fmaxf(acc[r] + bias, 0.f);
    }
  }
}

// ------------------------------- launcher ----------------------------------

extern "C" void kernel_launch(void* const* d_in, const int* in_sizes, int n_in,
                              void* d_out, int out_size, void* d_ws, size_t ws_size,
                              hipStream_t stream) {
  const float* x     = (const float*)d_in[0];
  const float* pos   = (const float*)d_in[1];
  const int*   eidx  = (const int*)d_in[2];
  const float* W_in  = (const float*)d_in[3];
  const float* b_in  = (const float*)d_in[4];
  const float* ln_g  = (const float*)d_in[5];
  const float* ln_b  = (const float*)d_in[6];
  const float* W_lin = (const float*)d_in[7];
  const float* W_src = (const float*)d_in[8];
  const float* W_dst = (const float*)d_in[9];
  const float* pn_W1 = (const float*)d_in[10];
  const float* pn_b1 = (const float*)d_in[11];
  const float* pn_W2 = (const float*)d_in[12];
  const float* pn_b2 = (const float*)d_in[13];
  const float* an_W1 = (const float*)d_in[14];
  const float* an_b1 = (const float*)d_in[15];
  const float* an_W2 = (const float*)d_in[16];
  const float* an_b2 = (const float*)d_in[17];
  const float* W_out = (const float*)d_in[18];
  const float* b_out = (const float*)d_in[19];
  float* out = (float*)d_out;

  int N = in_sizes[0] / 64;
  int E = in_sizes[2] / 2;
  const int* src = eidx;
  const int* dst = eidx + E;

  char* w = (char*)d_ws;
  auto alloc = [&](size_t bytes) -> void* {
    void* p = (void*)w;
    w += (bytes + 255) & ~(size_t)255;
    return p;
  };
  float* qg   = (float*)alloc((size_t)N * 64 * 4);
  float* kg   = (float*)alloc((size_t)N * 64 * 4);
  float* vg   = (float*)alloc((size_t)N * 64 * 4);
  float* sg   = (float*)alloc((size_t)N * 64 * 4);
  float* accg = (float*)alloc((size_t)N * 64 * 4);   // contiguous after sg
  int2* spair = (int2*)alloc((size_t)E * 8);
  unsigned short* wt = (unsigned short*)alloc(8 * 4608 * 2);
  int* hist   = (int*)alloc((size_t)N * 4);
  int* cursor = (int*)alloc((size_t)N * 4);
  int* bsum   = (int*)alloc(1024 * 4);
  int* incl   = (int*)accg;   // scan scratch aliased into accg (used first)

  int nb1 = (N + 1023) / 1024;               // <= 256 required by k_scan3
  int nodeBlocks = (N + 63) / 64;
  int histBlocks = (E + 255) / 256;
  int zcount = N * 32;                        // sg+accg in float4s
  int zBlocks = (zcount + 255) / 256;

  hipMemsetAsync(hist, 0, (size_t)N * 4, stream);
  k_prep_hist<<<8 + histBlocks, 256, 0, stream>>>(
      W_in, W_dst, W_src, W_lin, pn_W2, an_W1, an_W2, W_out, wt, dst, hist, E);
  k_node<<<nodeBlocks + nb1, 256, 0, stream>>>(
      x, wt, b_in, ln_g, ln_b, qg, kg, vg, N, hist, incl, bsum, nodeBlocks);
  k_scan3<<<nb1, 256, 0, stream>>>(incl, hist, bsum, cursor, N);
  k_scatter_zero<<<histBlocks + zBlocks, 256, 0, stream>>>(
      src, dst, cursor, spair, E, (float4*)sg, zcount, histBlocks);
  k_edge<<<(E + 63) / 64, 256, 0, stream>>>(spair, pos, qg, kg, vg,
                                            pn_W1, pn_b1, pn_W2, pn_b2,
                                            an_W1, an_b1, an_W2, an_b2,
                                            sg, accg, E);
  k_out<<<nodeBlocks, 256, 0, stream>>>(accg, sg, wt, b_out, out, N);
}

// Round 12
// 563.958 us; speedup vs baseline: 1.0416x; 1.0416x over previous
//
#include <hip/hip_runtime.h>

// ---------------------------------------------------------------------------
// PointTransformerBlock, MI355X.  R12 = R11 + bf16 q/k/v storage:
//  - qg/kg/vg stored as bf16 (halves k_edge's random-gather bytes 820->410MB
//    worst case; 25.6MB working set -> higher L2 hit rate; 2 instead of 4
//    outstanding 16B loads per operand per lane).  ai is bf16 before MFMA
//    anyway, so added rounding is same-scale (absmax ~0.05 < 0.0988).
//  - k_edge: R8 body (proven: VGPR 68 / occ 33%); cross-tile pipelines
//    rejected (R9/R10: prefetch VGPRs drop 3->2 blocks/CU, net loss).
//  - Tail: R10/R11 launcher (hist in k_prep, scan1 in k_node, scan2 in
//    scan3, zeroing in scatter).
//  MFMA layouts (HW-verified, guide §3): A[m=lane&15][k=quad*8+j],
//  B[k=quad*8+j][n=lane&15], C/D col=lane&15 row=quad*4+reg.
// ---------------------------------------------------------------------------

typedef __bf16 bf16x8 __attribute__((ext_vector_type(8)));
typedef float f32x4 __attribute__((ext_vector_type(4)));

__device__ inline unsigned short f2bf(float f) {
  return __builtin_bit_cast(unsigned short, (__bf16)f);   // v_cvt (RNE)
}
__device__ inline float bf2f(unsigned short s) {
  return __uint_as_float(((unsigned int)s) << 16);
}
__device__ inline bf16x8 ld_bf8(const unsigned short* p) {
  union { uint4 i; bf16x8 v; } u;
  u.i = *(const uint4*)p;
  return u.v;
}

// --------------------- prep kernel with fused histogram --------------------

__global__ __launch_bounds__(256) void k_prep_hist(
    const float* __restrict__ W_in, const float* __restrict__ W_dst,
    const float* __restrict__ W_src, const float* __restrict__ W_lin,
    const float* __restrict__ pn_W2, const float* __restrict__ an_W1,
    const float* __restrict__ an_W2, const float* __restrict__ W_out,
    unsigned short* __restrict__ wt,
    const int* __restrict__ dst, int* __restrict__ hist, int E) {
  int t = threadIdx.x;
  if (blockIdx.x >= 8) {
    int e = (blockIdx.x - 8) * 256 + t;
    if (e < E) atomicAdd(&hist[dst[e]], 1);
    return;
  }
  const float* Ws[8] = {W_in, W_dst, W_src, W_lin, pn_W2, an_W1, an_W2, W_out};
  const float* W = Ws[blockIdx.x];
  unsigned short* o = wt + (size_t)blockIdx.x * 4608;
#pragma unroll
  for (int i = 0; i < 16; ++i) {
    int e = i * 256 + t;           // e = k*64 + n  (coalesced read)
    int k = e >> 6, n = e & 63;
    o[n * 72 + k] = f2bf(W[e]);
  }
}

// ------------------------------ sort kernels -------------------------------

// scan3 with inline block-offset: reduce bsum[0..blockIdx) in-block.
// Requires gridDim <= 256 (N <= 262144).
__global__ __launch_bounds__(256) void k_scan3(
    const int* __restrict__ incl, const int* __restrict__ hist,
    const int* __restrict__ bsum, int* __restrict__ cursor, int N) {
  __shared__ int red[256];
  int t = threadIdx.x;
  red[t] = (t < (int)blockIdx.x) ? bsum[t] : 0;
  __syncthreads();
#pragma unroll
  for (int off = 128; off; off >>= 1) {
    if (t < off) red[t] += red[t + off];
    __syncthreads();
  }
  int bo = red[0];
  int base = blockIdx.x * 1024 + t * 4;
#pragma unroll
  for (int i = 0; i < 4; ++i) {
    int id = base + i;
    if (id < N) cursor[id] = bo + incl[id] - hist[id];
  }
}

// scatter with fused sg/accg zeroing (sibling blocks).
__global__ void k_scatter_zero(const int* __restrict__ src,
                               const int* __restrict__ dst,
                               int* __restrict__ cursor,
                               int2* __restrict__ spair, int E,
                               float4* __restrict__ zbase, int zcount,
                               int scatterBlocks) {
  int t = threadIdx.x;
  if ((int)blockIdx.x >= scatterBlocks) {
    int i = ((int)blockIdx.x - scatterBlocks) * 256 + t;
    if (i < zcount) zbase[i] = make_float4(0.f, 0.f, 0.f, 0.f);
    return;
  }
  int e = blockIdx.x * 256 + t;
  if (e < E) {
    int s = src[e], d = dst[e];
    int p = atomicAdd(&cursor[d], 1);
    spair[p] = make_int2(s, d);
  }
}

// ---------------- node kernel (MFMA, bf16 q/k/v out) with fused scan1 ------

__global__ __launch_bounds__(256) void k_node(
    const float* __restrict__ x, const unsigned short* __restrict__ wt,
    const float* __restrict__ b_in, const float* __restrict__ ln_g,
    const float* __restrict__ ln_b,
    unsigned short* __restrict__ qg, unsigned short* __restrict__ kg,
    unsigned short* __restrict__ vg,
    int N, const int* __restrict__ hist, int* __restrict__ incl,
    int* __restrict__ bsum, int nodeBlocks) {
  int t = threadIdx.x;

  // ---- fused scan1 blocks ----
  if ((int)blockIdx.x >= nodeBlocks) {
    __shared__ int sd[256];
    int bid = blockIdx.x - nodeBlocks;
    int base = bid * 1024 + t * 4;
    int v[4]; int ts = 0;
#pragma unroll
    for (int i = 0; i < 4; ++i) {
      int idx = base + i;
      v[i] = (idx < N) ? hist[idx] : 0;
      ts += v[i];
    }
    sd[t] = ts;
    __syncthreads();
    for (int off = 1; off < 256; off <<= 1) {
      int xv = (t >= off) ? sd[t - off] : 0;
      __syncthreads();
      sd[t] += xv;
      __syncthreads();
    }
    int run = sd[t] - ts;
#pragma unroll
    for (int i = 0; i < 4; ++i) {
      run += v[i];
      int idx = base + i;
      if (idx < N) incl[idx] = run;
    }
    if (t == 255) bsum[bid] = sd[255];
    return;
  }

  __shared__ __align__(16) unsigned short WALL[4 * 64 * 72];
  __shared__ __align__(16) unsigned short HT[64 * 72];
  __shared__ float LNG[64], LNB[64], BIN[64];

  int lane = t & 63, wv = t >> 6;
  int nl = lane & 15, q = lane >> 4;
  int w16 = wv * 16;
  int n0g = blockIdx.x * 64;

  {
    const uint4* s4 = (const uint4*)wt;
    uint4* d4 = (uint4*)WALL;
#pragma unroll
    for (int i = 0; i < 9; ++i) d4[i * 256 + t] = s4[i * 256 + t];
  }
  if (t < 64) { LNG[t] = ln_g[t]; LNB[t] = ln_b[t]; BIN[t] = b_in[t]; }

  int row = n0g + w16 + nl;
  bf16x8 a[2];
#pragma unroll
  for (int s = 0; s < 2; ++s) {
    union { unsigned short u[8]; bf16x8 v; } fa;
    if (row < N) {
      int kb = s * 32 + q * 8;
      float4 xa = *(const float4*)(x + (size_t)row * 64 + kb);
      float4 xb = *(const float4*)(x + (size_t)row * 64 + kb + 4);
      fa.u[0] = f2bf(xa.x); fa.u[1] = f2bf(xa.y);
      fa.u[2] = f2bf(xa.z); fa.u[3] = f2bf(xa.w);
      fa.u[4] = f2bf(xb.x); fa.u[5] = f2bf(xb.y);
      fa.u[6] = f2bf(xb.z); fa.u[7] = f2bf(xb.w);
    } else {
#pragma unroll
      for (int j = 0; j < 8; ++j) fa.u[j] = 0;
    }
    a[s] = fa.v;
  }
  __syncthreads();

  f32x4 h[4];
#pragma unroll
  for (int n0 = 0; n0 < 4; ++n0) {
    f32x4 acc = {0.f, 0.f, 0.f, 0.f};
    acc = __builtin_amdgcn_mfma_f32_16x16x32_bf16(
        a[0], ld_bf8(&WALL[(n0 * 16 + nl) * 72 + q * 8]), acc, 0, 0, 0);
    acc = __builtin_amdgcn_mfma_f32_16x16x32_bf16(
        a[1], ld_bf8(&WALL[(n0 * 16 + nl) * 72 + 32 + q * 8]), acc, 0, 0, 0);
    float bias = BIN[n0 * 16 + nl];
#pragma unroll
    for (int r = 0; r < 4; ++r) acc[r] = fmaxf(acc[r] + bias, 0.f);
    h[n0] = acc;
  }

#pragma unroll
  for (int r = 0; r < 4; ++r) {
    float sv = 0.f, sq = 0.f;
#pragma unroll
    for (int n0 = 0; n0 < 4; ++n0) {
      float v = h[n0][r];
      sv += v; sq += v * v;
    }
    sv += __shfl_xor(sv, 1); sq += __shfl_xor(sq, 1);
    sv += __shfl_xor(sv, 2); sq += __shfl_xor(sq, 2);
    sv += __shfl_xor(sv, 4); sq += __shfl_xor(sq, 4);
    sv += __shfl_xor(sv, 8); sq += __shfl_xor(sq, 8);
    float mu = sv * (1.f / 64.f);
    float var = sq * (1.f / 64.f) - mu * mu;
    float rs = rsqrtf(var + 1e-5f);
    int crow = w16 + q * 4 + r;
#pragma unroll
    for (int n0 = 0; n0 < 4; ++n0) {
      int col = n0 * 16 + nl;
      float hv = (h[n0][r] - mu) * rs * LNG[col] + LNB[col];
      HT[crow * 72 + col] = f2bf(hv);
    }
  }

  a[0] = ld_bf8(&HT[(w16 + nl) * 72 + q * 8]);
  a[1] = ld_bf8(&HT[(w16 + nl) * 72 + 32 + q * 8]);

  unsigned short* Og[3] = {qg, kg, vg};
#pragma unroll
  for (int m = 0; m < 3; ++m) {
    const unsigned short* Wm = WALL + (m + 1) * 4608;
#pragma unroll
    for (int n0 = 0; n0 < 4; ++n0) {
      f32x4 acc = {0.f, 0.f, 0.f, 0.f};
      acc = __builtin_amdgcn_mfma_f32_16x16x32_bf16(
          a[0], ld_bf8(&Wm[(n0 * 16 + nl) * 72 + q * 8]), acc, 0, 0, 0);
      acc = __builtin_amdgcn_mfma_f32_16x16x32_bf16(
          a[1], ld_bf8(&Wm[(n0 * 16 + nl) * 72 + 32 + q * 8]), acc, 0, 0, 0);
      int col = n0 * 16 + nl;
#pragma unroll
      for (int r = 0; r < 4; ++r) {
        int grow = n0g + w16 + q * 4 + r;
        if (grow < N) Og[m][(size_t)grow * 64 + col] = f2bf(acc[r]);
      }
    }
  }
}

// ------------- edge kernel (MFMA, R8 body; bf16 q/k/v gathers) -------------

__global__ __launch_bounds__(256) void k_edge(
    const int2* __restrict__ spair, const float* __restrict__ pos,
    const unsigned short* __restrict__ qg, const unsigned short* __restrict__ kg,
    const unsigned short* __restrict__ vg,
    const float* __restrict__ pn_W1, const float* __restrict__ pn_b1,
    const float* __restrict__ pn_W2, const float* __restrict__ pn_b2,
    const float* __restrict__ an_W1, const float* __restrict__ an_b1,
    const float* __restrict__ an_W2, const float* __restrict__ an_b2,
    float* __restrict__ sg, float* __restrict__ accg, int E) {
  __shared__ __align__(16) unsigned short WPN2[64 * 72];
  __shared__ __align__(16) unsigned short WAN1[64 * 72];
  __shared__ __align__(16) unsigned short WAN2[64 * 72];
  __shared__ __align__(16) unsigned short SD[64 * 72];   // delta (bf16)
  __shared__ __align__(16) unsigned short SB[64 * 72];   // a1, then ex (bf16)
  __shared__ float PD[64 * 4];
  __shared__ float W1[3 * 64];
  __shared__ float B1[64], B2[64], AB1[64], AB2[64];
  __shared__ int Ss[64], Sd[64];

  int t = threadIdx.x;
  int lane = t & 63, wv = t >> 6;
  int nl = lane & 15, q = lane >> 4;
  int w16 = wv * 16;
  long e0 = (long)blockIdx.x * 64;

  // ---- per-lane early gather: my A-frag row's q/k rows (pre-barrier) ----
  long er = e0 + w16 + nl;
  int2 my = (er < E) ? spair[er] : make_int2(0, 0);
  const unsigned short* qr = qg + (size_t)my.y * 64;
  const unsigned short* kr = kg + (size_t)my.x * 64;
  bf16x8 qf[2], kf[2];
#pragma unroll
  for (int s = 0; s < 2; ++s) {
    int kb = s * 32 + q * 8;
    qf[s] = ld_bf8(qr + kb);
    kf[s] = ld_bf8(kr + kb);
  }

  // ---- stage weights bf16 [n][k] stride 72 (VALU filler over gather lat) --
  {
    int n = t & 63, k0 = (t >> 6) * 16;
#pragma unroll
    for (int i = 0; i < 16; ++i) {
      int k = k0 + i;
      WPN2[n * 72 + k] = f2bf(pn_W2[k * 64 + n]);
      WAN1[n * 72 + k] = f2bf(an_W1[k * 64 + n]);
      WAN2[n * 72 + k] = f2bf(an_W2[k * 64 + n]);
    }
  }
  if (t < 192) W1[t] = pn_W1[t];
  if (t < 64) {
    B1[t] = pn_b1[t];  B2[t] = pn_b2[t];
    AB1[t] = an_b1[t]; AB2[t] = an_b2[t];
    long e = e0 + t;
    int2 sd2 = (e < E) ? spair[e] : make_int2(0, 0);
    Ss[t] = sd2.x; Sd[t] = sd2.y;
    PD[t * 4 + 0] = pos[sd2.y * 3 + 0] - pos[sd2.x * 3 + 0];
    PD[t * 4 + 1] = pos[sd2.y * 3 + 1] - pos[sd2.x * 3 + 1];
    PD[t * 4 + 2] = pos[sd2.y * 3 + 2] - pos[sd2.x * 3 + 2];
  }
  __syncthreads();

  // ---- v prefetch for the reduction (rows wave-private: qq == wv) ----
  float vpre[16];
  {
    int c = t & 63, qq = t >> 6;
#pragma unroll
    for (int i = 0; i < 16; ++i)
      vpre[i] = bf2f(vg[(size_t)Ss[qq * 16 + i] * 64 + c]);
  }

  bf16x8 a[2];

  // ---- pos-MLP layer1 (K=3) straight into A-frag registers ----
  {
    int row = w16 + nl;
    float p0 = PD[row * 4 + 0], p1 = PD[row * 4 + 1], p2 = PD[row * 4 + 2];
#pragma unroll
    for (int s = 0; s < 2; ++s) {
      union { unsigned short u[8]; bf16x8 v; } fa;
      int kb = s * 32 + q * 8;
#pragma unroll
      for (int j = 0; j < 8; ++j) {
        int c = kb + j;
        float val = fmaf(p0, W1[c],
                    fmaf(p1, W1[64 + c],
                    fmaf(p2, W1[128 + c], B1[c])));
        fa.u[j] = f2bf(fmaxf(val, 0.f));
      }
      a[s] = fa.v;
    }
  }

  // ---- GEMM1: delta = relu(A1 @ pn_W2 + b2) -> SD (bf16) ----
#pragma unroll
  for (int n0 = 0; n0 < 4; ++n0) {
    f32x4 acc = {0.f, 0.f, 0.f, 0.f};
    acc = __builtin_amdgcn_mfma_f32_16x16x32_bf16(
        a[0], ld_bf8(&WPN2[(n0 * 16 + nl) * 72 + q * 8]), acc, 0, 0, 0);
    acc = __builtin_amdgcn_mfma_f32_16x16x32_bf16(
        a[1], ld_bf8(&WPN2[(n0 * 16 + nl) * 72 + 32 + q * 8]), acc, 0, 0, 0);
    int col = n0 * 16 + nl;
    float bias = B2[col];
#pragma unroll
    for (int r = 0; r < 4; ++r) {
      int row = w16 + q * 4 + r;
      SD[row * 72 + col] = f2bf(fmaxf(acc[r] + bias, 0.f));
    }
  }

  // ---- build ai = q[dst]-k[src]+delta in A-frag layout ----
  {
    int row = w16 + nl;
#pragma unroll
    for (int s = 0; s < 2; ++s) {
      int kb = s * 32 + q * 8;
      bf16x8 d8 = ld_bf8(&SD[row * 72 + kb]);
      union { unsigned short u[8]; bf16x8 v; } fa;
#pragma unroll
      for (int j = 0; j < 8; ++j)
        fa.u[j] = f2bf((float)qf[s][j] - (float)kf[s][j] + (float)d8[j]);
      a[s] = fa.v;
    }
  }

  // ---- GEMM2: a1 = relu(ai @ an_W1 + an_b1) -> SB (bf16) ----
#pragma unroll
  for (int n0 = 0; n0 < 4; ++n0) {
    f32x4 acc = {0.f, 0.f, 0.f, 0.f};
    acc = __builtin_amdgcn_mfma_f32_16x16x32_bf16(
        a[0], ld_bf8(&WAN1[(n0 * 16 + nl) * 72 + q * 8]), acc, 0, 0, 0);
    acc = __builtin_amdgcn_mfma_f32_16x16x32_bf16(
        a[1], ld_bf8(&WAN1[(n0 * 16 + nl) * 72 + 32 + q * 8]), acc, 0, 0, 0);
    int col = n0 * 16 + nl;
    float bias = AB1[col];
#pragma unroll
    for (int r = 0; r < 4; ++r) {
      int row = w16 + q * 4 + r;
      SB[row * 72 + col] = f2bf(fmaxf(acc[r] + bias, 0.f));
    }
  }

  // ---- GEMM3: alpha = relu(a1 @ an_W2 + an_b2); ex = exp(alpha) -> SB ----
  // (wave-private SB rows; DS ops in-order per wave, no barrier needed)
  a[0] = ld_bf8(&SB[(w16 + nl) * 72 + q * 8]);
  a[1] = ld_bf8(&SB[(w16 + nl) * 72 + 32 + q * 8]);
#pragma unroll
  for (int n0 = 0; n0 < 4; ++n0) {
    f32x4 acc = {0.f, 0.f, 0.f, 0.f};
    acc = __builtin_amdgcn_mfma_f32_16x16x32_bf16(
        a[0], ld_bf8(&WAN2[(n0 * 16 + nl) * 72 + q * 8]), acc, 0, 0, 0);
    acc = __builtin_amdgcn_mfma_f32_16x16x32_bf16(
        a[1], ld_bf8(&WAN2[(n0 * 16 + nl) * 72 + 32 + q * 8]), acc, 0, 0, 0);
    int col = n0 * 16 + nl;
    float bias = AB2[col];
#pragma unroll
    for (int r = 0; r < 4; ++r) {
      int row = w16 + q * 4 + r;
      long e = e0 + row;
      float al = fmaxf(acc[r] + bias, 0.f);
      float ex = (e < E) ? __expf(al) : 0.f;
      SB[row * 72 + col] = f2bf(ex);
    }
  }

  // ---- segmented per-dst-run reduction (rows wave-private: no barrier) ----
  {
    int c = t & 63, qq = t >> 6;
    int r0 = qq * 16;
    int cur = Sd[r0];
    float ssum = 0.f, asum = 0.f;
#pragma unroll
    for (int r = r0; r < r0 + 16; ++r) {
      int d = Sd[r];
      if (d != cur) {
        if (ssum != 0.f) {
          atomicAdd(&sg[(size_t)cur * 64 + c], ssum);
          atomicAdd(&accg[(size_t)cur * 64 + c], asum);
        }
        cur = d; ssum = 0.f; asum = 0.f;
      }
      float ex = bf2f(SB[r * 72 + c]);
      float pay = vpre[r - r0] + bf2f(SD[r * 72 + c]);
      ssum += ex;
      asum = fmaf(ex, pay, asum);
    }
    if (ssum != 0.f) {
      atomicAdd(&sg[(size_t)cur * 64 + c], ssum);
      atomicAdd(&accg[(size_t)cur * 64 + c], asum);
    }
  }
}

// ------------------------- out kernel (MFMA) -------------------------------

__global__ __launch_bounds__(256) void k_out(const float* __restrict__ accg,
                                             const float* __restrict__ sg,
                                             const unsigned short* __restrict__ wt,
                                             const float* __restrict__ b,
                                             float* __restrict__ out, int N) {
  __shared__ __align__(16) unsigned short WO[64 * 72];
  __shared__ float BO[64];
  int t = threadIdx.x;
  int lane = t & 63, wv = t >> 6;
  int nl = lane & 15, q = lane >> 4;
  int w16 = wv * 16;
  int n0g = blockIdx.x * 64;

  {
    const uint4* s4 = (const uint4*)(wt + 7 * 4608);  // matrix 7 = W_out
    uint4* d4 = (uint4*)WO;
#pragma unroll
    for (int i = 0; i < 3; ++i) {
      int idx = i * 256 + t;
      if (idx < 576) d4[idx] = s4[idx];
    }
  }
  if (t < 64) BO[t] = b[t];

  int row = n0g + w16 + nl;
  bf16x8 a[2];
#pragma unroll
  for (int s = 0; s < 2; ++s) {
    union { unsigned short u[8]; bf16x8 v; } fa;
    if (row < N) {
      int kb = s * 32 + q * 8;
      float4 na = *(const float4*)(accg + (size_t)row * 64 + kb);
      float4 nb = *(const float4*)(accg + (size_t)row * 64 + kb + 4);
      float4 da = *(const float4*)(sg + (size_t)row * 64 + kb);
      float4 db = *(const float4*)(sg + (size_t)row * 64 + kb + 4);
      fa.u[0] = f2bf(na.x / (da.x + 1e-16f));
      fa.u[1] = f2bf(na.y / (da.y + 1e-16f));
      fa.u[2] = f2bf(na.z / (da.z + 1e-16f));
      fa.u[3] = f2bf(na.w / (da.w + 1e-16f));
      fa.u[4] = f2bf(nb.x / (db.x + 1e-16f));
      fa.u[5] = f2bf(nb.y / (db.y + 1e-16f));
      fa.u[6] = f2bf(nb.z / (db.z + 1e-16f));
      fa.u[7] = f2bf(nb.w / (db.w + 1e-16f));
    } else {
#pragma unroll
      for (int j = 0; j < 8; ++j) fa.u[j] = 0;
    }
    a[s] = fa.v;
  }
  __syncthreads();

#pragma unroll
  for (int n0 = 0; n0 < 4; ++n0) {
    f32x4 acc = {0.f, 0.f, 0.f, 0.f};
    acc = __builtin_amdgcn_mfma_f32_16x16x32_bf16(
        a[0], ld_bf8(&WO[(n0 * 16 + nl) * 72 + q * 8]), acc, 0, 0, 0);
    acc = __builtin_amdgcn_mfma_f32_16x16x32_bf16(
        a[1], ld_bf8(&WO[(n0 * 16 + nl) * 72 + 32 + q * 8]), acc, 0, 0, 0);
    int col = n0 * 16 + nl;
    float bias = BO[col];
#pragma unroll
    for (int r = 0; r < 4; ++r) {
      int grow = n0g + w16 + q * 4 + r;
      if (grow < N) out[(size_t)grow * 64 + col] = fmaxf(acc[r] + bias, 0.f);
    }
  }
}

// ------------------------------- launcher ----------------------------------

extern "C" void kernel_launch(void* const* d_in, const int* in_sizes, int n_in,
                              void* d_out, int out_size, void* d_ws, size_t ws_size,
                              hipStream_t stream) {
  const float* x     = (const float*)d_in[0];
  const float* pos   = (const float*)d_in[1];
  const int*   eidx  = (const int*)d_in[2];
  const float* W_in  = (const float*)d_in[3];
  const float* b_in  = (const float*)d_in[4];
  const float* ln_g  = (const float*)d_in[5];
  const float* ln_b  = (const float*)d_in[6];
  const float* W_lin = (const float*)d_in[7];
  const float* W_src = (const float*)d_in[8];
  const float* W_dst = (const float*)d_in[9];
  const float* pn_W1 = (const float*)d_in[10];
  const float* pn_b1 = (const float*)d_in[11];
  const float* pn_W2 = (const float*)d_in[12];
  const float* pn_b2 = (const float*)d_in[13];
  const float* an_W1 = (const float*)d_in[14];
  const float* an_b1 = (const float*)d_in[15];
  const float* an_W2 = (const float*)d_in[16];
  const float* an_b2 = (const float*)d_in[17];
  const float* W_out = (const float*)d_in[18];
  const float* b_out = (const float*)d_in[19];
  float* out = (float*)d_out;

  int N = in_sizes[0] / 64;
  int E = in_sizes[2] / 2;
  const int* src = eidx;
  const int* dst = eidx + E;

  char* w = (char*)d_ws;
  auto alloc = [&](size_t bytes) -> void* {
    void* p = (void*)w;
    w += (bytes + 255) & ~(size_t)255;
    return p;
  };
  unsigned short* qg = (unsigned short*)alloc((size_t)N * 64 * 2);
  unsigned short* kg = (unsigned short*)alloc((size_t)N * 64 * 2);
  unsigned short* vg = (unsigned short*)alloc((size_t)N * 64 * 2);
  float* sg   = (float*)alloc((size_t)N * 64 * 4);
  float* accg = (float*)alloc((size_t)N * 64 * 4);   // contiguous after sg
  int2* spair = (int2*)alloc((size_t)E * 8);
  unsigned short* wt = (unsigned short*)alloc(8 * 4608 * 2);
  int* hist   = (int*)alloc((size_t)N * 4);
  int* cursor = (int*)alloc((size_t)N * 4);
  int* bsum   = (int*)alloc(1024 * 4);
  int* incl   = (int*)accg;   // scan scratch aliased into accg (used first)

  int nb1 = (N + 1023) / 1024;               // <= 256 required by k_scan3
  int nodeBlocks = (N + 63) / 64;
  int histBlocks = (E + 255) / 256;
  int zcount = N * 32;                        // sg+accg in float4s
  int zBlocks = (zcount + 255) / 256;

  hipMemsetAsync(hist, 0, (size_t)N * 4, stream);
  k_prep_hist<<<8 + histBlocks, 256, 0, stream>>>(
      W_in, W_dst, W_src, W_lin, pn_W2, an_W1, an_W2, W_out, wt, dst, hist, E);
  k_node<<<nodeBlocks + nb1, 256, 0, stream>>>(
      x, wt, b_in, ln_g, ln_b, qg, kg, vg, N, hist, incl, bsum, nodeBlocks);
  k_scan3<<<nb1, 256, 0, stream>>>(incl, hist, bsum, cursor, N);
  k_scatter_zero<<<histBlocks + zBlocks, 256, 0, stream>>>(
      src, dst, cursor, spair, E, (float4*)sg, zcount, histBlocks);
  k_edge<<<(E + 63) / 64, 256, 0, stream>>>(spair, pos, qg, kg, vg,
                                            pn_W1, pn_b1, pn_W2, pn_b2,
                                            an_W1, an_b1, an_W2, an_b2,
                                            sg, accg, E);
  k_out<<<nodeBlocks, 256, 0, stream>>>(accg, sg, wt, b_out, out, N);
}